// Round 7
// baseline (159.608 us; speedup 1.0000x reference)
//
#include <hip/hip_runtime.h>
#include <cmath>

#define EMBED   1024
#define EPB     8
#define NB      64
#define KTOP    2
#define TPW     8               // tokens per wave-chunk (binned main kernel)

// ---------------------------------------------------------------------------
// Prep pipeline (r1/r5-verified machinery, parallelized):
//   K_hist    : 16 blocks, LDS pre-aggregation -> global atomicAdd on count
//   K_scan    : 1 wave, shuffle scan -> bstart/soffs/cpre/chunk2b
//   K_scatter : 16 blocks, global atomic cursors -> bucket-major perm[]
// ---------------------------------------------------------------------------
__global__ void hist_kernel(const int* __restrict__ op, int ntok,
                            int* __restrict__ count) {
    __shared__ int hc[NB];
    int tid = threadIdx.x;
    if (tid < NB) hc[tid] = 0;
    __syncthreads();
    for (int i = blockIdx.x * blockDim.x + tid; i < ntok;
         i += gridDim.x * blockDim.x) {
        int b = min(max(op[i], 0), NB - 1);
        atomicAdd(&hc[b], 1);
    }
    __syncthreads();
    if (tid < NB && hc[tid]) atomicAdd(&count[tid], hc[tid]);
}

__global__ void scan_kernel(const int* __restrict__ count,
                            int* __restrict__ bstart,
                            int* __restrict__ soffs,
                            int* __restrict__ cpre,
                            int* __restrict__ chunk2b) {
    int tid = threadIdx.x;                     // 0..63, one wave
    int c   = count[tid];
    int nch = (c + TPW - 1) / TPW;
    int ic = c, in = nch;                      // inclusive scans
#pragma unroll
    for (int off = 1; off < 64; off <<= 1) {
        int vc = __shfl_up(ic, off, 64);
        int vn = __shfl_up(in, off, 64);
        if (tid >= off) { ic += vc; in += vn; }
    }
    int bs = ic - c;                           // exclusive
    int cp = in - nch;
    bstart[tid] = bs;
    soffs[tid]  = bs;
    cpre[tid]   = cp;
    if (tid == 63) cpre[NB] = in;              // total chunks
    for (int j = 0; j < nch; ++j) chunk2b[cp + j] = tid;
}

__global__ void scatter_kernel(const int* __restrict__ op, int ntok,
                               int* __restrict__ soffs,
                               int* __restrict__ perm) {
    for (int i = blockIdx.x * blockDim.x + threadIdx.x; i < ntok;
         i += gridDim.x * blockDim.x) {
        int b = min(max(op[i], 0), NB - 1);
        int pos = atomicAdd(&soffs[b], 1);
        perm[pos] = i;
    }
}

// ---------------------------------------------------------------------------
// Named-register key state + OPAQUE PIN: round 6 proved LLVM rematerializes
// readonly loads inside the token loop (VGPR_Count=100 < the 128 keys need),
// silently re-streaming keys 8x. An asm with "+v" outputs cannot be
// rematerialized -> the 32 KB key set is genuinely VGPR-resident and its 32
// loads are all in flight before the single drain at the pin.
// ---------------------------------------------------------------------------
#define LOADK(e) \
    float4 k##e##_0 = kb[(e)*256 +       lane]; \
    float4 k##e##_1 = kb[(e)*256 +  64 + lane]; \
    float4 k##e##_2 = kb[(e)*256 + 128 + lane]; \
    float4 k##e##_3 = kb[(e)*256 + 192 + lane];

#define PIN4(v) asm volatile("" : "+v"(v.x), "+v"(v.y), "+v"(v.z), "+v"(v.w))
#define PINK(e) PIN4(k##e##_0); PIN4(k##e##_1); PIN4(k##e##_2); PIN4(k##e##_3);

#define SQE(e) \
    float s##e = k##e##_0.x*k##e##_0.x + k##e##_0.y*k##e##_0.y + k##e##_0.z*k##e##_0.z + k##e##_0.w*k##e##_0.w; \
    s##e += k##e##_1.x*k##e##_1.x + k##e##_1.y*k##e##_1.y + k##e##_1.z*k##e##_1.z + k##e##_1.w*k##e##_1.w; \
    s##e += k##e##_2.x*k##e##_2.x + k##e##_2.y*k##e##_2.y + k##e##_2.z*k##e##_2.z + k##e##_2.w*k##e##_2.w; \
    s##e += k##e##_3.x*k##e##_3.x + k##e##_3.y*k##e##_3.y + k##e##_3.z*k##e##_3.z + k##e##_3.w*k##e##_3.w;

#define REDS(off) \
    s0 += __shfl_xor(s0, off, 64); s1 += __shfl_xor(s1, off, 64); \
    s2 += __shfl_xor(s2, off, 64); s3 += __shfl_xor(s3, off, 64); \
    s4 += __shfl_xor(s4, off, 64); s5 += __shfl_xor(s5, off, 64); \
    s6 += __shfl_xor(s6, off, 64); s7 += __shfl_xor(s7, off, 64);

// A/B software pipeline: h buffer P is 4 named float4s loaded one body ahead.
#define LOADH(P, tk) { \
    const float4* hrow_ = (const float4*)(h + (size_t)(tk) * EMBED); \
    h##P##0 = hrow_[lane];       h##P##1 = hrow_[ 64 + lane]; \
    h##P##2 = hrow_[128 + lane]; h##P##3 = hrow_[192 + lane]; }

#define ACC1(e, c, P) \
    d##e += h##P##c.x * k##e##_##c.x + h##P##c.y * k##e##_##c.y + \
            h##P##c.z * k##e##_##c.z + h##P##c.w * k##e##_##c.w;

#define STEPC(c, P) \
    hh += h##P##c.x*h##P##c.x + h##P##c.y*h##P##c.y + h##P##c.z*h##P##c.z + h##P##c.w*h##P##c.w; \
    ACC1(0,c,P) ACC1(1,c,P) ACC1(2,c,P) ACC1(3,c,P) \
    ACC1(4,c,P) ACC1(5,c,P) ACC1(6,c,P) ACC1(7,c,P)

#define REDD(off) \
    hh += __shfl_xor(hh, off, 64); \
    d0 += __shfl_xor(d0, off, 64); d1 += __shfl_xor(d1, off, 64); \
    d2 += __shfl_xor(d2, off, 64); d3 += __shfl_xor(d3, off, 64); \
    d4 += __shfl_xor(d4, off, 64); d5 += __shfl_xor(d5, off, 64); \
    d6 += __shfl_xor(d6, off, 64); d7 += __shfl_xor(d7, off, 64);

#define T1(e) if (ex##e > v1) { v1 = ex##e; i1 = (e); }
#define T2(e) if ((e) != i1 && ex##e > v2) { v2 = ex##e; i2 = (e); }

// Full per-token body: dots+norm, 6-stage butterfly, softmax+top-2, store.
// FP expression order identical to the round-5/6 PASSED kernels.
#define BODY(P, t) { \
    float hh = 0.f; \
    float d0 = 0.f, d1 = 0.f, d2 = 0.f, d3 = 0.f; \
    float d4 = 0.f, d5 = 0.f, d6 = 0.f, d7 = 0.f; \
    STEPC(0,P) STEPC(1,P) STEPC(2,P) STEPC(3,P) \
    REDD(32) REDD(16) REDD(8) REDD(4) REDD(2) REDD(1) \
    float rh = 1.0f / fmaxf(sqrtf(hh), 1e-12f); \
    float sc0 = d0 * rh * rke0, sc1 = d1 * rh * rke1; \
    float sc2 = d2 * rh * rke2, sc3 = d3 * rh * rke3; \
    float sc4 = d4 * rh * rke4, sc5 = d5 * rh * rke5; \
    float sc6 = d6 * rh * rke6, sc7 = d7 * rh * rke7; \
    float m = -1e30f; \
    m = fmaxf(m, sc0); m = fmaxf(m, sc1); m = fmaxf(m, sc2); m = fmaxf(m, sc3); \
    m = fmaxf(m, sc4); m = fmaxf(m, sc5); m = fmaxf(m, sc6); m = fmaxf(m, sc7); \
    float ex0 = expf(sc0 - m), ex1 = expf(sc1 - m); \
    float ex2 = expf(sc2 - m), ex3 = expf(sc3 - m); \
    float ex4 = expf(sc4 - m), ex5 = expf(sc5 - m); \
    float ex6 = expf(sc6 - m), ex7 = expf(sc7 - m); \
    float Z = 0.f; \
    Z += ex0; Z += ex1; Z += ex2; Z += ex3; \
    Z += ex4; Z += ex5; Z += ex6; Z += ex7; \
    float v1 = ex0; int i1 = 0; \
    T1(1) T1(2) T1(3) T1(4) T1(5) T1(6) T1(7) \
    float v2 = (i1 == 0) ? ex1 : ex0; \
    int   i2 = (i1 == 0) ? 1 : 0; \
    T2(0) T2(1) T2(2) T2(3) T2(4) T2(5) T2(6) T2(7) \
    if (lane == 0 && (base + (t)) < end) { \
        float p1 = v1 / Z; \
        float p2 = v2 / Z; \
        float ws = p1 + p2 + 1e-9f; \
        int tk = tok[t]; \
        ((float2*)out_gid)[tk] = \
            make_float2((float)(b * EPB + i1), (float)(b * EPB + i2)); \
        ((float2*)out_w)[tk] = make_float2(p1 / ws, p2 / ws); \
    } }

// ---------------------------------------------------------------------------
// Main kernel: one wave per chunk of TPW=8 same-bucket tokens; 4 chunks per
// 256-thread block. Keys pinned in 128 VGPRs; h double-buffered one token
// ahead. launch_bounds(256,2) -> 256-VGPR cap, 8 waves/CU over 528 blocks.
// ---------------------------------------------------------------------------
__global__ __launch_bounds__(256, 2) void router_regkey_kernel(
    const float* __restrict__ h, const float* __restrict__ ek,
    const int* __restrict__ perm, const int* __restrict__ bstart_g,
    const int* __restrict__ cnt_g, const int* __restrict__ cpre_g,
    const int* __restrict__ chunk2b,
    float* __restrict__ out_gid, float* __restrict__ out_w) {
    int wid  = (int)((blockIdx.x * blockDim.x + threadIdx.x) >> 6);
    int lane = threadIdx.x & 63;
    int total = cpre_g[NB];
    if (wid >= total) return;

    int b    = chunk2b[wid];
    int lc   = wid - cpre_g[b];
    int base = bstart_g[b] + lc * TPW;
    int end  = bstart_g[b] + cnt_g[b];

    // ---- keys -> 128 pinned VGPRs: 32 concurrent coalesced 1 KB loads ----
    const float4* kb = (const float4*)ek + (size_t)b * (EPB * EMBED / 4);
    LOADK(0) LOADK(1) LOADK(2) LOADK(3) LOADK(4) LOADK(5) LOADK(6) LOADK(7)
    PINK(0) PINK(1) PINK(2) PINK(3) PINK(4) PINK(5) PINK(6) PINK(7)

    // ---- key rnorms from registers (verified FP order) ----
    SQE(0) SQE(1) SQE(2) SQE(3) SQE(4) SQE(5) SQE(6) SQE(7)
    REDS(32) REDS(16) REDS(8) REDS(4) REDS(2) REDS(1)
    float rke0 = 1.0f / fmaxf(sqrtf(s0), 1e-12f);
    float rke1 = 1.0f / fmaxf(sqrtf(s1), 1e-12f);
    float rke2 = 1.0f / fmaxf(sqrtf(s2), 1e-12f);
    float rke3 = 1.0f / fmaxf(sqrtf(s3), 1e-12f);
    float rke4 = 1.0f / fmaxf(sqrtf(s4), 1e-12f);
    float rke5 = 1.0f / fmaxf(sqrtf(s5), 1e-12f);
    float rke6 = 1.0f / fmaxf(sqrtf(s6), 1e-12f);
    float rke7 = 1.0f / fmaxf(sqrtf(s7), 1e-12f);

    // ---- token indices (wave-uniform) ----
    int tok[TPW];
#pragma unroll
    for (int t = 0; t < TPW; ++t) tok[t] = perm[min(base + t, end - 1)];

    // ---- A/B pipelined token stream: loads issued one body ahead ----
    float4 hA0, hA1, hA2, hA3;
    float4 hB0, hB1, hB2, hB3;
    LOADH(A, tok[0])
    LOADH(B, tok[1])  BODY(A, 0)
    LOADH(A, tok[2])  BODY(B, 1)
    LOADH(B, tok[3])  BODY(A, 2)
    LOADH(A, tok[4])  BODY(B, 3)
    LOADH(B, tok[5])  BODY(A, 4)
    LOADH(A, tok[6])  BODY(B, 5)
    LOADH(B, tok[7])  BODY(A, 6)
    BODY(B, 7)
}

// ---------------------------------------------------------------------------
// Fallback path (workspace too small): round-4 verified 2-kernel version.
// ---------------------------------------------------------------------------
__global__ void key_rnorm_kernel(const float* __restrict__ ek,
                                 float* __restrict__ rnorm) {
    int wave = (int)((blockIdx.x * blockDim.x + threadIdx.x) >> 6);
    int lane = threadIdx.x & 63;
    if (wave >= NB * EPB) return;
    const float4* row = (const float4*)(ek + (size_t)wave * EMBED);
    float s = 0.f;
#pragma unroll
    for (int c = 0; c < 4; ++c) {
        float4 v = row[c * 64 + lane];
        s += v.x * v.x + v.y * v.y + v.z * v.z + v.w * v.w;
    }
#pragma unroll
    for (int off = 32; off; off >>= 1) s += __shfl_xor(s, off, 64);
    if (lane == 0) rnorm[wave] = 1.0f / fmaxf(sqrtf(s), 1e-12f);
}

__global__ __launch_bounds__(256, 6) void router_duo_kernel(
    const float* __restrict__ h, const int* __restrict__ op,
    const float* __restrict__ ek, const float* __restrict__ rk,
    float* __restrict__ out_gid, float* __restrict__ out_w, int ntok) {
    int gtid = blockIdx.x * blockDim.x + threadIdx.x;
    int wid  = gtid >> 6;
    int lane = threadIdx.x & 63;
    int half = lane >> 5;
    int r    = lane & 31;
    int tq   = wid * 2 + half;
    int tc   = min(tq, ntok - 1);

    int b = op[tc];
    b = min(max(b, 0), NB - 1);

    const float4* hrow = (const float4*)(h + (size_t)tc * EMBED);
    const float4* kb   = (const float4*)ek + (size_t)b * (EPB * EMBED / 4);

    float dot[EPB] = {0.f, 0.f, 0.f, 0.f, 0.f, 0.f, 0.f, 0.f};
    float hh = 0.f;
#pragma unroll
    for (int i = 0; i < 8; ++i) {
        float4 a = hrow[i * 32 + r];
        hh += a.x * a.x + a.y * a.y + a.z * a.z + a.w * a.w;
#pragma unroll
        for (int e = 0; e < EPB; ++e) {
            float4 kvv = kb[e * 256 + i * 32 + r];
            dot[e] += a.x * kvv.x + a.y * kvv.y + a.z * kvv.z + a.w * kvv.w;
        }
    }
#pragma unroll
    for (int off = 16; off; off >>= 1) {
        hh += __shfl_xor(hh, off, 64);
#pragma unroll
        for (int e = 0; e < EPB; ++e) dot[e] += __shfl_xor(dot[e], off, 64);
    }
    float rh = 1.0f / fmaxf(sqrtf(hh), 1e-12f);
    float sc[EPB];
    float m = -1e30f;
#pragma unroll
    for (int e = 0; e < EPB; ++e) {
        sc[e] = dot[e] * rh * rk[b * EPB + e];
        m = fmaxf(m, sc[e]);
    }
    float ex[EPB];
    float Z = 0.f;
#pragma unroll
    for (int e = 0; e < EPB; ++e) { ex[e] = expf(sc[e] - m); Z += ex[e]; }
    int i1 = 0;
#pragma unroll
    for (int e = 1; e < EPB; ++e) if (ex[e] > ex[i1]) i1 = e;
    int i2 = (i1 == 0) ? 1 : 0;
#pragma unroll
    for (int e = 0; e < EPB; ++e)
        if (e != i1 && ex[e] > ex[i2]) i2 = e;
    if (r == 0 && tq < ntok) {
        float p1 = ex[i1] / Z;
        float p2 = ex[i2] / Z;
        float ws = p1 + p2 + 1e-9f;
        ((float2*)out_gid)[tq] =
            make_float2((float)(b * EPB + i1), (float)(b * EPB + i2));
        ((float2*)out_w)[tq] = make_float2(p1 / ws, p2 / ws);
    }
}

extern "C" void kernel_launch(void* const* d_in, const int* in_sizes, int n_in,
                              void* d_out, int out_size, void* d_ws, size_t ws_size,
                              hipStream_t stream) {
    const float* h     = (const float*)d_in[0];
    const int*   op_id = (const int*)  d_in[1];
    const float* ek    = (const float*)d_in[2];

    int ntok  = in_sizes[1];                   // B*T tokens
    int maxch = NB + (ntok + TPW - 1) / TPW;   // upper bound on chunks

    float* out_gid = (float*)d_out;
    float* out_w   = out_gid + (size_t)ntok * KTOP;

    // Workspace: rk[512] (fallback) | count[64] | bstart[64] | soffs[64]
    //            | cpre[65] | chunk2b[maxch] | perm[ntok]
    float* rk      = (float*)d_ws;
    int*   count   = (int*)(rk + 512);
    int*   bstart  = count  + NB;
    int*   soffs   = bstart + NB;
    int*   cpre    = soffs  + NB;
    int*   chunk2b = cpre + (NB + 1);
    int*   perm    = chunk2b + maxch;
    size_t need    = ((size_t)(512 + 3 * NB + NB + 1 + maxch) + (size_t)ntok) * 4;

    if (ws_size < need) {
        key_rnorm_kernel<<<128, 256, 0, stream>>>(ek, rk);
        int blocks2 = (ntok + 7) / 8;
        router_duo_kernel<<<blocks2, 256, 0, stream>>>(h, op_id, ek, rk,
                                                       out_gid, out_w, ntok);
        return;
    }

    // 0: zero bucket counters
    hipMemsetAsync(count, 0, NB * sizeof(int), stream);
    // 1: histogram (parallel, LDS-preaggregated global atomics)
    hist_kernel<<<16, 256, 0, stream>>>(op_id, ntok, count);
    // 2: scan (one wave)
    scan_kernel<<<1, 64, 0, stream>>>(count, bstart, soffs, cpre, chunk2b);
    // 3: scatter (parallel, global atomic cursors)
    scatter_kernel<<<16, 256, 0, stream>>>(op_id, ntok, soffs, perm);
    // 4: pinned-register-key router, 4 chunks per 256-thread block
    int blocks = (maxch * 64 + 255) / 256;
    router_regkey_kernel<<<blocks, 256, 0, stream>>>(
        h, ek, perm, bstart, count, cpre, chunk2b, out_gid, out_w);
}

// Round 11
// 143.613 us; speedup vs baseline: 1.1114x; 1.1114x over previous
//
#include <hip/hip_runtime.h>
#include <cmath>

#define EMBED 1024
#define EPB   8
#define NB    64
#define KTOP  2
#define CHT   16            // tokens per chunk (one block per chunk)
#define HB    16            // histogram / scatter blocks

// ---------------------------------------------------------------------------
// zero_kernel: zero the bucket counters. Replaces hipMemsetAsync — the only
// non-kernel stream op in the launch sequence of the 3 failed benches; all
// passing rounds except r7 used pure kernel launches. Disambiguation step.
// ---------------------------------------------------------------------------
__global__ void zero_kernel(int* __restrict__ count) {
    if (threadIdx.x < NB) count[threadIdx.x] = 0;
}

// ---------------------------------------------------------------------------
// prep1: blocks [0,128) = key rnorms (4 rows per block, verified body);
//        blocks [128,128+HB) = token histogram (verified body).
// ---------------------------------------------------------------------------
__global__ __launch_bounds__(256) void prep1_kernel(
    const float* __restrict__ ek, float* __restrict__ rnorm,
    const int* __restrict__ op, int ntok, int* __restrict__ count) {
    int tid = threadIdx.x;
    if (blockIdx.x < 128) {
        int row  = blockIdx.x * 4 + (tid >> 6);      // < 512
        int lane = tid & 63;
        const float4* r4 = (const float4*)(ek + (size_t)row * EMBED);
        float s = 0.f;
#pragma unroll
        for (int c = 0; c < 4; ++c) {
            float4 v = r4[c * 64 + lane];
            s += v.x * v.x + v.y * v.y + v.z * v.z + v.w * v.w;
        }
#pragma unroll
        for (int off = 32; off; off >>= 1) s += __shfl_xor(s, off, 64);
        if (lane == 0) rnorm[row] = 1.0f / fmaxf(sqrtf(s), 1e-12f);
        return;
    }
    __shared__ int hc[NB];
    int hb = blockIdx.x - 128;
    if (tid < NB) hc[tid] = 0;
    __syncthreads();
    for (int i = hb * 256 + tid; i < ntok; i += HB * 256) {
        int b = min(max(op[i], 0), NB - 1);
        atomicAdd(&hc[b], 1);
    }
    __syncthreads();
    if (tid < NB && hc[tid]) atomicAdd(&count[tid], hc[tid]);
}

__global__ void scan_kernel(const int* __restrict__ count,
                            int* __restrict__ bstart, int* __restrict__ soffs,
                            int* __restrict__ cpre, int* __restrict__ chunk2b) {
    int tid = threadIdx.x;                           // one wave
    int c   = count[tid];
    int nch = (c + CHT - 1) / CHT;
    int ic = c, in = nch;
#pragma unroll
    for (int off = 1; off < 64; off <<= 1) {
        int vc = __shfl_up(ic, off, 64);
        int vn = __shfl_up(in, off, 64);
        if (tid >= off) { ic += vc; in += vn; }
    }
    int bs = ic - c, cp = in - nch;
    bstart[tid] = bs; soffs[tid] = bs; cpre[tid] = cp;
    if (tid == 63) cpre[NB] = in;
    for (int j = 0; j < nch; ++j) chunk2b[cp + j] = tid;
}

__global__ void scatter_kernel(const int* __restrict__ op, int ntok,
                               int* __restrict__ soffs, int* __restrict__ perm) {
    for (int i = blockIdx.x * blockDim.x + threadIdx.x; i < ntok;
         i += gridDim.x * blockDim.x) {
        int b = min(max(op[i], 0), NB - 1);
        int pos = atomicAdd(&soffs[b], 1);
        perm[pos] = i;
    }
}

// ---------------------------------------------------------------------------
// Main kernel: one 256-thread block per chunk of CHT=16 same-bucket tokens.
// Keys staged to LDS once per chunk (32 KB = 512 line-requests amortized to
// 32 lines/token). Each wave register-blocks 4 tokens x 8 experts: per iter
// 4 coalesced h loads (the irreducible 64 lines/token) + 8 ds_read_b128 of
// keys SHARED across the 4 tokens -> 36 named accumulators, ~100 VGPR.
// Cuts L1-miss line-requests/token ~3-6x vs all previous rounds, which is
// the empirically-binding resource (~0.2-0.3 lines/cyc/CU in r2-r7).
// ---------------------------------------------------------------------------
#define D4(a,b) ((a).x*(b).x + (a).y*(b).y + (a).z*(b).z + (a).w*(b).w)

#define ITER(i) { \
    int off = (i)*64 + lane; \
    float4 a0 = hr0[off]; float4 a1 = hr1[off]; \
    float4 a2 = hr2[off]; float4 a3 = hr3[off]; \
    float4 q0 = skv[0*256+off]; float4 q1 = skv[1*256+off]; \
    float4 q2 = skv[2*256+off]; float4 q3 = skv[3*256+off]; \
    float4 q4 = skv[4*256+off]; float4 q5 = skv[5*256+off]; \
    float4 q6 = skv[6*256+off]; float4 q7 = skv[7*256+off]; \
    hh0 += D4(a0,a0); hh1 += D4(a1,a1); hh2 += D4(a2,a2); hh3 += D4(a3,a3); \
    d00 += D4(a0,q0); d01 += D4(a0,q1); d02 += D4(a0,q2); d03 += D4(a0,q3); \
    d04 += D4(a0,q4); d05 += D4(a0,q5); d06 += D4(a0,q6); d07 += D4(a0,q7); \
    d10 += D4(a1,q0); d11 += D4(a1,q1); d12 += D4(a1,q2); d13 += D4(a1,q3); \
    d14 += D4(a1,q4); d15 += D4(a1,q5); d16 += D4(a1,q6); d17 += D4(a1,q7); \
    d20 += D4(a2,q0); d21 += D4(a2,q1); d22 += D4(a2,q2); d23 += D4(a2,q3); \
    d24 += D4(a2,q4); d25 += D4(a2,q5); d26 += D4(a2,q6); d27 += D4(a2,q7); \
    d30 += D4(a3,q0); d31 += D4(a3,q1); d32 += D4(a3,q2); d33 += D4(a3,q3); \
    d34 += D4(a3,q4); d35 += D4(a3,q5); d36 += D4(a3,q6); d37 += D4(a3,q7); }

#define RED(o) \
    hh0 += __shfl_xor(hh0,o,64); hh1 += __shfl_xor(hh1,o,64); \
    hh2 += __shfl_xor(hh2,o,64); hh3 += __shfl_xor(hh3,o,64); \
    d00 += __shfl_xor(d00,o,64); d01 += __shfl_xor(d01,o,64); \
    d02 += __shfl_xor(d02,o,64); d03 += __shfl_xor(d03,o,64); \
    d04 += __shfl_xor(d04,o,64); d05 += __shfl_xor(d05,o,64); \
    d06 += __shfl_xor(d06,o,64); d07 += __shfl_xor(d07,o,64); \
    d10 += __shfl_xor(d10,o,64); d11 += __shfl_xor(d11,o,64); \
    d12 += __shfl_xor(d12,o,64); d13 += __shfl_xor(d13,o,64); \
    d14 += __shfl_xor(d14,o,64); d15 += __shfl_xor(d15,o,64); \
    d16 += __shfl_xor(d16,o,64); d17 += __shfl_xor(d17,o,64); \
    d20 += __shfl_xor(d20,o,64); d21 += __shfl_xor(d21,o,64); \
    d22 += __shfl_xor(d22,o,64); d23 += __shfl_xor(d23,o,64); \
    d24 += __shfl_xor(d24,o,64); d25 += __shfl_xor(d25,o,64); \
    d26 += __shfl_xor(d26,o,64); d27 += __shfl_xor(d27,o,64); \
    d30 += __shfl_xor(d30,o,64); d31 += __shfl_xor(d31,o,64); \
    d32 += __shfl_xor(d32,o,64); d33 += __shfl_xor(d33,o,64); \
    d34 += __shfl_xor(d34,o,64); d35 += __shfl_xor(d35,o,64); \
    d36 += __shfl_xor(d36,o,64); d37 += __shfl_xor(d37,o,64);

#define SEL4(x0,x1,x2,x3) ((g==0)?(x0):(g==1)?(x1):(g==2)?(x2):(x3))
#define T1(e) if (ex##e > v1) { v1 = ex##e; i1 = (e); }
#define T2(e) if ((e) != i1 && ex##e > v2) { v2 = ex##e; i2 = (e); }

__global__ __launch_bounds__(256, 4) void router_chunk_kernel(
    const float* __restrict__ h, const float* __restrict__ ek,
    const float* __restrict__ rk, const int* __restrict__ perm,
    const int* __restrict__ bstart_g, const int* __restrict__ cnt_g,
    const int* __restrict__ cpre_g, const int* __restrict__ chunk2b,
    float* __restrict__ out_gid, float* __restrict__ out_w) {
    __shared__ float sk[EPB * EMBED];                // 32 KB
    int tid  = threadIdx.x;
    int lane = tid & 63;
    int wave = tid >> 6;
    int g    = lane >> 4;                            // token group 0..3
    int r16  = lane & 15;

    int gch = blockIdx.x;
    if (gch >= cpre_g[NB]) return;                   // block-uniform branch
    int b    = chunk2b[gch];
    int lc   = gch - cpre_g[b];
    int base = bstart_g[b] + lc * CHT;
    int end  = bstart_g[b] + cnt_g[b];

    // stage keys: 512 coalesced float4 stores, linear (conflict-free)
    const float4* src = (const float4*)ek + (size_t)b * (EPB * EMBED / 4);
    float4* dst = (float4*)sk;
#pragma unroll
    for (int j = 0; j < 8; ++j) dst[j * 256 + tid] = src[j * 256 + tid];

    // wave-uniform per-bucket rnorms + token ids
    float rk0 = rk[b*EPB+0], rk1 = rk[b*EPB+1], rk2 = rk[b*EPB+2], rk3 = rk[b*EPB+3];
    float rk4 = rk[b*EPB+4], rk5 = rk[b*EPB+5], rk6 = rk[b*EPB+6], rk7 = rk[b*EPB+7];
    int s0i = base + wave * 4;
    int tok0 = perm[min(s0i + 0, end - 1)];
    int tok1 = perm[min(s0i + 1, end - 1)];
    int tok2 = perm[min(s0i + 2, end - 1)];
    int tok3 = perm[min(s0i + 3, end - 1)];
    const float4* hr0 = (const float4*)(h + (size_t)tok0 * EMBED);
    const float4* hr1 = (const float4*)(h + (size_t)tok1 * EMBED);
    const float4* hr2 = (const float4*)(h + (size_t)tok2 * EMBED);
    const float4* hr3 = (const float4*)(h + (size_t)tok3 * EMBED);
    __syncthreads();

    const float4* skv = (const float4*)sk;
    float hh0=0.f, hh1=0.f, hh2=0.f, hh3=0.f;
    float d00=0.f,d01=0.f,d02=0.f,d03=0.f,d04=0.f,d05=0.f,d06=0.f,d07=0.f;
    float d10=0.f,d11=0.f,d12=0.f,d13=0.f,d14=0.f,d15=0.f,d16=0.f,d17=0.f;
    float d20=0.f,d21=0.f,d22=0.f,d23=0.f,d24=0.f,d25=0.f,d26=0.f,d27=0.f;
    float d30=0.f,d31=0.f,d32=0.f,d33=0.f,d34=0.f,d35=0.f,d36=0.f,d37=0.f;

    ITER(0) ITER(1) ITER(2) ITER(3)

    RED(32) RED(16) RED(8) RED(4) RED(2) RED(1)

    // ---- tail: 16-lane group g handles token g (uniform within group) ----
    float thh = SEL4(hh0, hh1, hh2, hh3);
    float t0 = SEL4(d00, d10, d20, d30);
    float t1 = SEL4(d01, d11, d21, d31);
    float t2 = SEL4(d02, d12, d22, d32);
    float t3 = SEL4(d03, d13, d23, d33);
    float t4 = SEL4(d04, d14, d24, d34);
    float t5 = SEL4(d05, d15, d25, d35);
    float t6 = SEL4(d06, d16, d26, d36);
    float t7 = SEL4(d07, d17, d27, d37);
    int   tk = SEL4(tok0, tok1, tok2, tok3);
    int   gi = s0i + g;

    float rh = 1.0f / fmaxf(sqrtf(thh), 1e-12f);
    float sc0 = t0 * rh * rk0, sc1 = t1 * rh * rk1;
    float sc2 = t2 * rh * rk2, sc3 = t3 * rh * rk3;
    float sc4 = t4 * rh * rk4, sc5 = t5 * rh * rk5;
    float sc6 = t6 * rh * rk6, sc7 = t7 * rh * rk7;
    float m = -1e30f;
    m = fmaxf(m, sc0); m = fmaxf(m, sc1); m = fmaxf(m, sc2); m = fmaxf(m, sc3);
    m = fmaxf(m, sc4); m = fmaxf(m, sc5); m = fmaxf(m, sc6); m = fmaxf(m, sc7);
    float ex0 = expf(sc0 - m), ex1 = expf(sc1 - m);
    float ex2 = expf(sc2 - m), ex3 = expf(sc3 - m);
    float ex4 = expf(sc4 - m), ex5 = expf(sc5 - m);
    float ex6 = expf(sc6 - m), ex7 = expf(sc7 - m);
    float Z = 0.f;
    Z += ex0; Z += ex1; Z += ex2; Z += ex3;
    Z += ex4; Z += ex5; Z += ex6; Z += ex7;
    float v1 = ex0; int i1 = 0;
    T1(1) T1(2) T1(3) T1(4) T1(5) T1(6) T1(7)
    float v2 = (i1 == 0) ? ex1 : ex0;
    int   i2 = (i1 == 0) ? 1 : 0;
    T2(0) T2(1) T2(2) T2(3) T2(4) T2(5) T2(6) T2(7)

    if (r16 == 0 && gi < end) {
        float p1 = v1 / Z, p2 = v2 / Z;
        float ws = p1 + p2 + 1e-9f;
        ((float2*)out_gid)[tk] =
            make_float2((float)(b * EPB + i1), (float)(b * EPB + i2));
        ((float2*)out_w)[tk] = make_float2(p1 / ws, p2 / ws);
    }
}

// ---------------------------------------------------------------------------
// Fallback path (workspace too small): round-4 verified 2-kernel version.
// ---------------------------------------------------------------------------
__global__ void key_rnorm_kernel(const float* __restrict__ ek,
                                 float* __restrict__ rnorm) {
    int wave = (int)((blockIdx.x * blockDim.x + threadIdx.x) >> 6);
    int lane = threadIdx.x & 63;
    if (wave >= NB * EPB) return;
    const float4* row = (const float4*)(ek + (size_t)wave * EMBED);
    float s = 0.f;
#pragma unroll
    for (int c = 0; c < 4; ++c) {
        float4 v = row[c * 64 + lane];
        s += v.x * v.x + v.y * v.y + v.z * v.z + v.w * v.w;
    }
#pragma unroll
    for (int off = 32; off; off >>= 1) s += __shfl_xor(s, off, 64);
    if (lane == 0) rnorm[wave] = 1.0f / fmaxf(sqrtf(s), 1e-12f);
}

__global__ __launch_bounds__(256, 6) void router_duo_kernel(
    const float* __restrict__ h, const int* __restrict__ op,
    const float* __restrict__ ek, const float* __restrict__ rk,
    float* __restrict__ out_gid, float* __restrict__ out_w, int ntok) {
    int gtid = blockIdx.x * blockDim.x + threadIdx.x;
    int wid  = gtid >> 6;
    int lane = threadIdx.x & 63;
    int half = lane >> 5;
    int r    = lane & 31;
    int tq   = wid * 2 + half;
    int tc   = min(tq, ntok - 1);
    int b = op[tc];
    b = min(max(b, 0), NB - 1);
    const float4* hrow = (const float4*)(h + (size_t)tc * EMBED);
    const float4* kb   = (const float4*)ek + (size_t)b * (EPB * EMBED / 4);
    float dot[EPB] = {0.f,0.f,0.f,0.f,0.f,0.f,0.f,0.f};
    float hh = 0.f;
#pragma unroll
    for (int i = 0; i < 8; ++i) {
        float4 a = hrow[i * 32 + r];
        hh += a.x*a.x + a.y*a.y + a.z*a.z + a.w*a.w;
#pragma unroll
        for (int e = 0; e < EPB; ++e) {
            float4 kv = kb[e * 256 + i * 32 + r];
            dot[e] += a.x*kv.x + a.y*kv.y + a.z*kv.z + a.w*kv.w;
        }
    }
#pragma unroll
    for (int off = 16; off; off >>= 1) {
        hh += __shfl_xor(hh, off, 64);
#pragma unroll
        for (int e = 0; e < EPB; ++e) dot[e] += __shfl_xor(dot[e], off, 64);
    }
    float rh = 1.0f / fmaxf(sqrtf(hh), 1e-12f);
    float sc[EPB];
    float m = -1e30f;
#pragma unroll
    for (int e = 0; e < EPB; ++e) {
        sc[e] = dot[e] * rh * rk[b * EPB + e];
        m = fmaxf(m, sc[e]);
    }
    float ex[EPB];
    float Z = 0.f;
#pragma unroll
    for (int e = 0; e < EPB; ++e) { ex[e] = expf(sc[e] - m); Z += ex[e]; }
    int i1 = 0;
#pragma unroll
    for (int e = 1; e < EPB; ++e) if (ex[e] > ex[i1]) i1 = e;
    int i2 = (i1 == 0) ? 1 : 0;
#pragma unroll
    for (int e = 0; e < EPB; ++e)
        if (e != i1 && ex[e] > ex[i2]) i2 = e;
    if (r == 0 && tq < ntok) {
        float p1 = ex[i1] / Z, p2 = ex[i2] / Z;
        float ws = p1 + p2 + 1e-9f;
        ((float2*)out_gid)[tq] =
            make_float2((float)(b * EPB + i1), (float)(b * EPB + i2));
        ((float2*)out_w)[tq] = make_float2(p1 / ws, p2 / ws);
    }
}

extern "C" void kernel_launch(void* const* d_in, const int* in_sizes, int n_in,
                              void* d_out, int out_size, void* d_ws, size_t ws_size,
                              hipStream_t stream) {
    const float* h     = (const float*)d_in[0];
    const int*   op_id = (const int*)  d_in[1];
    const float* ek    = (const float*)d_in[2];

    int ntok  = in_sizes[1];                         // B*T tokens
    int maxch = NB + (ntok + CHT - 1) / CHT;         // chunk upper bound

    float* out_gid = (float*)d_out;
    float* out_w   = out_gid + (size_t)ntok * KTOP;

    // Workspace: rk[512] | count[64] | bstart[64] | soffs[64] | cpre[65]
    //            | chunk2b[maxch] | perm[ntok]
    float* rk      = (float*)d_ws;
    int*   count   = (int*)(rk + 512);
    int*   bstart  = count  + NB;
    int*   soffs   = bstart + NB;
    int*   cpre    = soffs  + NB;
    int*   chunk2b = cpre + (NB + 1);
    int*   perm    = chunk2b + maxch;
    size_t need    = ((size_t)(512 + 3 * NB + NB + 1 + maxch) + (size_t)ntok) * 4;

    if (ws_size < need) {
        key_rnorm_kernel<<<128, 256, 0, stream>>>(ek, rk);
        int blocks2 = (ntok + 7) / 8;
        router_duo_kernel<<<blocks2, 256, 0, stream>>>(h, op_id, ek, rk,
                                                       out_gid, out_w, ntok);
        return;
    }

    // 0: zero bucket counters (kernel, not memsetAsync — disambiguation)
    zero_kernel<<<1, 64, 0, stream>>>(count);
    // 1: rnorm (blocks 0..127) + histogram (blocks 128..143)
    prep1_kernel<<<128 + HB, 256, 0, stream>>>(ek, rk, op_id, ntok, count);
    // 2: scan (one wave)
    scan_kernel<<<1, 64, 0, stream>>>(count, bstart, soffs, cpre, chunk2b);
    // 3: scatter into bucket-major perm
    scatter_kernel<<<HB, 256, 0, stream>>>(op_id, ntok, soffs, perm);
    // 4: chunked LDS-key router, one block per 16-token chunk
    router_chunk_kernel<<<maxch, 256, 0, stream>>>(
        h, ek, rk, perm, bstart, count, cpre, chunk2b, out_gid, out_w);
}